// Round 2
// baseline (457.583 us; speedup 1.0000x reference)
//
#include <hip/hip_runtime.h>

// MoE top-2 FFN, split-bf16 MFMA. Round 2:
//  - h pre-split to bf16 hi/lo by ffn1 (same numerics as before)
//  - global_load_lds DMA staging with pre-swizzled sources (rule 21)
//  - ffn1 128x128 tiles / 8 waves; ffn2 64x256 tiles / 8 waves, K-split x4
//  - wave-per-token gate, vectorized transpose

#define T_TOKENS 4096
#define D_MOD 512
#define N_EXP 8
#define D_FF 2048
#define TPAD 128         // expert padding (= ffn1 row tile; ffn2 uses 64)
#define P_CAP 9216       // 72*128 >= 8192 + 8*127 worst case

typedef __attribute__((ext_vector_type(4))) float f32x4_t;
typedef __attribute__((ext_vector_type(8))) short sh8;
typedef __attribute__((ext_vector_type(4))) short sh4;
typedef __attribute__((ext_vector_type(4))) unsigned short us4;

__device__ __forceinline__ unsigned short f2bh(float f) {
  unsigned u = __float_as_uint(f);
  return (unsigned short)((u + 0x7FFFu + ((u >> 16) & 1u)) >> 16);  // RNE
}
__device__ __forceinline__ float bh2f(unsigned short h) {
  return __uint_as_float(((unsigned)h) << 16);
}
// rows are 128B (64 bf16); XOR-swizzle bits 4..6 by row&7
__device__ __forceinline__ int swz(int row, int b) {
  return row * 128 + (b ^ ((row & 7) << 4));
}
// 16B global->LDS DMA; dest = firstlane(l) + lane*16
__device__ __forceinline__ void gl_lds16(const void* g, void* l) {
  __builtin_amdgcn_global_load_lds(
      (const __attribute__((address_space(1))) unsigned int*)g,
      (__attribute__((address_space(3))) unsigned int*)l, 16, 0, 0);
}

// ---------------- routing ----------------

__global__ void k_init(int* counts, int* pair_token, float* pair_gate) {
  int idx = blockIdx.x * 256 + threadIdx.x;
  if (idx < P_CAP) { pair_token[idx] = -1; pair_gate[idx] = 0.f; }
  if (idx < N_EXP) counts[idx] = 0;
}

__global__ __launch_bounds__(256) void k_gate(const float* __restrict__ x,
    const float* __restrict__ Wg, const float* __restrict__ bg,
    int* __restrict__ top_i, float* __restrict__ gates, int* __restrict__ counts) {
  __shared__ float wg_s[D_MOD * N_EXP];   // transposed [e][d], 16KB
  int tid = threadIdx.x;
  for (int i = tid; i < D_MOD * N_EXP; i += 256)
    wg_s[(i & 7) * D_MOD + (i >> 3)] = Wg[i];
  __syncthreads();
  int lane = tid & 63, w = tid >> 6;
  int t = blockIdx.x * 4 + w;
  const float* xr = x + (size_t)t * D_MOD;
  float acc[8];
#pragma unroll
  for (int e = 0; e < 8; ++e) acc[e] = 0.f;
#pragma unroll
  for (int it = 0; it < 2; ++it) {
    int d = it * 256 + lane * 4;
    float4 xv = *(const float4*)(xr + d);
#pragma unroll
    for (int e = 0; e < 8; ++e) {
      float4 wv = *(const float4*)(wg_s + e * D_MOD + d);
      acc[e] += xv.x * wv.x + xv.y * wv.y + xv.z * wv.z + xv.w * wv.w;
    }
  }
#pragma unroll
  for (int m = 32; m >= 1; m >>= 1)
#pragma unroll
    for (int e = 0; e < 8; ++e) acc[e] += __shfl_xor(acc[e], m);
  if (lane == 0) {
#pragma unroll
    for (int e = 0; e < 8; ++e) acc[e] += bg[e];
    int e0 = 0; float m0 = acc[0];
#pragma unroll
    for (int e = 1; e < 8; ++e) if (acc[e] > m0) { m0 = acc[e]; e0 = e; }
    int e1 = -1; float m1 = -3.4e38f;
#pragma unroll
    for (int e = 0; e < 8; ++e) if (e != e0 && acc[e] > m1) { m1 = acc[e]; e1 = e; }
    float g0 = 1.f / (1.f + __expf(m1 - m0));
    float g1 = 1.f - g0;
    top_i[t * 2] = e0; top_i[t * 2 + 1] = e1;
    gates[t * 2] = g0; gates[t * 2 + 1] = g1;
    atomicAdd(&counts[e0], 1);
    atomicAdd(&counts[e1], 1);
  }
}

__global__ void k_scan(const int* counts, int* offsets, int* cursor) {
  if (threadIdx.x == 0 && blockIdx.x == 0) {
    int o = 0;
    for (int e = 0; e < N_EXP; ++e) {
      offsets[e] = o; cursor[e] = o;
      o += (counts[e] + TPAD - 1) & ~(TPAD - 1);
    }
    offsets[N_EXP] = o;
  }
}

__global__ void k_scatter(const int* top_i, const float* gates, int* cursor,
                          int* pair_token, float* pair_gate) {
  int t = blockIdx.x * 256 + threadIdx.x;
#pragma unroll
  for (int k = 0; k < 2; ++k) {
    int e = top_i[t * 2 + k];
    int pos = atomicAdd(&cursor[e], 1);
    pair_token[pos] = t;
    pair_gate[pos] = gates[t * 2 + k];
  }
}

__global__ void k_outinit(const int* __restrict__ top_i, const float* __restrict__ gates,
                          const float* __restrict__ b2, float* __restrict__ out) {
  int idx = blockIdx.x * 256 + threadIdx.x;    // T*512
  int t = idx >> 9, d = idx & 511;
  out[idx] = gates[t * 2] * b2[top_i[t * 2] * D_MOD + d] +
             gates[t * 2 + 1] * b2[top_i[t * 2 + 1] * D_MOD + d];
}

// -------- weight transpose + hi/lo split: W[e][R][C] -> Wt[e][C][R] --------

__global__ __launch_bounds__(256) void k_transpose(const float* __restrict__ W,
    unsigned short* __restrict__ Wh, unsigned short* __restrict__ Wl, int R, int C) {
  __shared__ float tile[32][33];
  int e = blockIdx.z;
  int c0 = blockIdx.x * 32, r0 = blockIdx.y * 32;
  const float* src = W + (size_t)e * R * C;
  int tx = threadIdx.x & 31, ty = threadIdx.x >> 5;
#pragma unroll
  for (int i = 0; i < 4; ++i) {
    int r = ty + i * 8;
    tile[r][tx] = src[(size_t)(r0 + r) * C + c0 + tx];
  }
  __syncthreads();
  int cl = threadIdx.x >> 3;        // 0..31 local col
  int r4 = (threadIdx.x & 7) * 4;   // 0,4,..28 local row base
  float v0 = tile[r4 + 0][cl], v1 = tile[r4 + 1][cl];
  float v2 = tile[r4 + 2][cl], v3 = tile[r4 + 3][cl];
  us4 hv = {f2bh(v0), f2bh(v1), f2bh(v2), f2bh(v3)};
  us4 lv = {f2bh(v0 - bh2f(hv.x)), f2bh(v1 - bh2f(hv.y)),
            f2bh(v2 - bh2f(hv.z)), f2bh(v3 - bh2f(hv.w))};
  size_t o = ((size_t)e * C + c0 + cl) * R + r0 + r4;
  *(us4*)(Wh + o) = hv;
  *(us4*)(Wl + o) = lv;
}

// -------- GEMM1: h[row][f] = relu( X[tok(row)] @ W1 + b1 ), split to hi/lo --------
// 128x128 tile, 8 waves (4r x 2c), wave tile 32x64, K=512 in 64-steps.

__global__ __launch_bounds__(512) void k_ffn1(const float* __restrict__ x,
    const unsigned short* __restrict__ W1h, const unsigned short* __restrict__ W1l,
    const float* __restrict__ b1, const int* __restrict__ pair_token,
    const int* __restrict__ offsets, unsigned short* __restrict__ h_hi,
    unsigned short* __restrict__ h_lo, int row_base) {
  int total = offsets[N_EXP];
  int row0 = row_base + blockIdx.x * TPAD;
  if (row0 >= total) return;
  int f0 = blockIdx.y * 128;
  int e = 0;
  while (offsets[e + 1] <= row0) ++e;

  __shared__ __align__(16) char lds[65536 + 512];
  short* Ah = (short*)lds;                  // 128 rows x 128B
  short* Al = (short*)(lds + 16384);
  short* Bh = (short*)(lds + 32768);        // 128 rows x 128B
  short* Bl = (short*)(lds + 49152);
  int* tok = (int*)(lds + 65536);

  int tid = threadIdx.x;
  if (tid < TPAD) tok[tid] = pair_token[row0 + tid];
  __syncthreads();

  int lane = tid & 63, wid = tid >> 6;
  int wr = wid & 3, wc = wid >> 2;
  int lrow = lane & 15, kblk = lane >> 4;
  const f32x4_t zero = {0.f, 0.f, 0.f, 0.f};
  f32x4_t acc[2][4];
#pragma unroll
  for (int a = 0; a < 2; ++a)
#pragma unroll
    for (int b = 0; b < 4; ++b) acc[a][b] = zero;

  const size_t wb = (size_t)e * D_FF * D_MOD;
  for (int ks = 0; ks < D_MOD / 64; ++ks) {
    int k0 = ks * 64;
    // B: DMA pre-split weights, source pre-XOR'd so linear LDS == swizzled image
#pragma unroll
    for (int i = 0; i < 2; ++i) {
      int idx = tid + i * 512;             // 1024 chunks = 128 cols x 8
      int col = idx >> 3;
      int sb = (((idx & 7) * 16) ^ ((col & 7) << 4)) >> 1;
      size_t g = wb + (size_t)(f0 + col) * D_MOD + k0 + sb;
      gl_lds16(W1h + g, (char*)Bh + idx * 16);
      gl_lds16(W1l + g, (char*)Bl + idx * 16);
    }
    // A: gathered token rows, fp32 -> bf16 hi/lo, swizzled ds_write
#pragma unroll
    for (int i = 0; i < 4; ++i) {
      int idx = tid + i * 512;             // 2048 float4 = 128 rows x 16
      int r = idx >> 4, c4 = idx & 15;
      int t_ = tok[r];
      float4 v = make_float4(0.f, 0.f, 0.f, 0.f);
      if (t_ >= 0) v = *(const float4*)(x + (size_t)t_ * D_MOD + k0 + c4 * 4);
      unsigned short h0 = f2bh(v.x), h1 = f2bh(v.y), h2 = f2bh(v.z), h3 = f2bh(v.w);
      sh4 hv = {(short)h0, (short)h1, (short)h2, (short)h3};
      sh4 lv = {(short)f2bh(v.x - bh2f(h0)), (short)f2bh(v.y - bh2f(h1)),
                (short)f2bh(v.z - bh2f(h2)), (short)f2bh(v.w - bh2f(h3))};
      int off = swz(r, c4 * 8);
      *(sh4*)((char*)Ah + off) = hv;
      *(sh4*)((char*)Al + off) = lv;
    }
    __syncthreads();
#pragma unroll
    for (int kk = 0; kk < 2; ++kk) {
      sh8 ah[2], al[2], bh[4], bl[4];
#pragma unroll
      for (int rt = 0; rt < 2; ++rt) {
        int row = wr * 32 + rt * 16 + lrow;
        int off = swz(row, kk * 64 + kblk * 16);
        ah[rt] = *(const sh8*)((char*)Ah + off);
        al[rt] = *(const sh8*)((char*)Al + off);
      }
#pragma unroll
      for (int ct = 0; ct < 4; ++ct) {
        int col = wc * 64 + ct * 16 + lrow;
        int off = swz(col, kk * 64 + kblk * 16);
        bh[ct] = *(const sh8*)((char*)Bh + off);
        bl[ct] = *(const sh8*)((char*)Bl + off);
      }
#pragma unroll
      for (int rt = 0; rt < 2; ++rt)
#pragma unroll
        for (int ct = 0; ct < 4; ++ct) {
          acc[rt][ct] = __builtin_amdgcn_mfma_f32_16x16x32_bf16(ah[rt], bh[ct], acc[rt][ct], 0, 0, 0);
          acc[rt][ct] = __builtin_amdgcn_mfma_f32_16x16x32_bf16(ah[rt], bl[ct], acc[rt][ct], 0, 0, 0);
          acc[rt][ct] = __builtin_amdgcn_mfma_f32_16x16x32_bf16(al[rt], bh[ct], acc[rt][ct], 0, 0, 0);
        }
    }
    __syncthreads();
  }
  // epilogue: relu(acc+b1) -> LDS (f32, swizzled) -> vectorized split store
  float* hs = (float*)lds;   // 128 x 128 f32 = 64KB
#pragma unroll
  for (int rt = 0; rt < 2; ++rt)
#pragma unroll
    for (int ct = 0; ct < 4; ++ct)
#pragma unroll
      for (int r = 0; r < 4; ++r) {
        int row = wr * 32 + rt * 16 + kblk * 4 + r;   // C/D: row=(l>>4)*4+reg
        int f = wc * 64 + ct * 16 + lrow;             // col = l&15
        float v = fmaxf(acc[rt][ct][r] + b1[e * D_FF + f0 + f], 0.f);
        hs[row * 128 + (f ^ ((row & 7) << 2))] = v;
      }
  __syncthreads();
  int crow = row0 - row_base;
#pragma unroll
  for (int i = 0; i < 8; ++i) {
    int idx = tid + i * 512;           // 4096 float4 = 128 rows x 32
    int r = idx >> 5, cc = idx & 31;
    float4 v = *(const float4*)(hs + r * 128 + ((cc * 4) ^ ((r & 7) << 2)));
    us4 hv = {f2bh(v.x), f2bh(v.y), f2bh(v.z), f2bh(v.w)};
    us4 lv = {f2bh(v.x - bh2f(hv.x)), f2bh(v.y - bh2f(hv.y)),
              f2bh(v.z - bh2f(hv.z)), f2bh(v.w - bh2f(hv.w))};
    size_t o = (size_t)(crow + r) * D_FF + f0 + cc * 4;
    *(us4*)(h_hi + o) = hv;
    *(us4*)(h_lo + o) = lv;
  }
}

// -------- GEMM2: out[tok(row)] += gate(row) * ( h @ W2 ), K-split x4 --------
// 64x256 tile, 8 waves (2r x 4c), wave tile 32x64, K-chunk 512 in 64-steps.

__global__ __launch_bounds__(512) void k_ffn2(const unsigned short* __restrict__ h_hi,
    const unsigned short* __restrict__ h_lo,
    const unsigned short* __restrict__ W2h, const unsigned short* __restrict__ W2l,
    const int* __restrict__ pair_token, const float* __restrict__ pair_gate,
    const int* __restrict__ offsets, float* __restrict__ out, int row_base) {
  int total = offsets[N_EXP];
  int row0 = row_base + blockIdx.x * 64;
  if (row0 >= total) return;
  int n0 = blockIdx.y * 256;
  int kcb = blockIdx.z * 512;
  int e = 0;
  while (offsets[e + 1] <= row0) ++e;

  __shared__ __align__(16) char lds[81920];
  short* Ah = (short*)lds;                  // 64 rows x 128B = 8KB
  short* Al = (short*)(lds + 8192);
  short* Bh = (short*)(lds + 16384);        // 256 rows x 128B = 32KB
  short* Bl = (short*)(lds + 49152);

  int tid = threadIdx.x;
  int lane = tid & 63, wid = tid >> 6;
  int wr = wid & 1, wc = wid >> 1;
  int lrow = lane & 15, kblk = lane >> 4;
  const f32x4_t zero = {0.f, 0.f, 0.f, 0.f};
  f32x4_t acc[2][4];
#pragma unroll
  for (int a = 0; a < 2; ++a)
#pragma unroll
    for (int b = 0; b < 4; ++b) acc[a][b] = zero;

  int crow = row0 - row_base;
  const size_t wb = (size_t)e * D_MOD * D_FF;
  for (int ks = 0; ks < 8; ++ks) {
    int k0 = kcb + ks * 64;
    {   // A: DMA pre-split h
      int r = tid >> 3;
      int sb = (((tid & 7) * 16) ^ ((r & 7) << 4)) >> 1;
      size_t g = (size_t)(crow + r) * D_FF + k0 + sb;
      gl_lds16(h_hi + g, (char*)Ah + tid * 16);
      gl_lds16(h_lo + g, (char*)Al + tid * 16);
    }
#pragma unroll
    for (int i = 0; i < 4; ++i) {         // B: 2048 chunks = 256 cols x 8
      int idx = tid + i * 512;
      int col = idx >> 3;
      int sb = (((idx & 7) * 16) ^ ((col & 7) << 4)) >> 1;
      size_t g = wb + (size_t)(n0 + col) * D_FF + k0 + sb;
      gl_lds16(W2h + g, (char*)Bh + idx * 16);
      gl_lds16(W2l + g, (char*)Bl + idx * 16);
    }
    __syncthreads();
#pragma unroll
    for (int kk = 0; kk < 2; ++kk) {
      sh8 ah[2], al[2], bh[4], bl[4];
#pragma unroll
      for (int rt = 0; rt < 2; ++rt) {
        int row = wr * 32 + rt * 16 + lrow;
        int off = swz(row, kk * 64 + kblk * 16);
        ah[rt] = *(const sh8*)((char*)Ah + off);
        al[rt] = *(const sh8*)((char*)Al + off);
      }
#pragma unroll
      for (int ct = 0; ct < 4; ++ct) {
        int col = wc * 64 + ct * 16 + lrow;
        int off = swz(col, kk * 64 + kblk * 16);
        bh[ct] = *(const sh8*)((char*)Bh + off);
        bl[ct] = *(const sh8*)((char*)Bl + off);
      }
#pragma unroll
      for (int rt = 0; rt < 2; ++rt)
#pragma unroll
        for (int ct = 0; ct < 4; ++ct) {
          acc[rt][ct] = __builtin_amdgcn_mfma_f32_16x16x32_bf16(ah[rt], bh[ct], acc[rt][ct], 0, 0, 0);
          acc[rt][ct] = __builtin_amdgcn_mfma_f32_16x16x32_bf16(ah[rt], bl[ct], acc[rt][ct], 0, 0, 0);
          acc[rt][ct] = __builtin_amdgcn_mfma_f32_16x16x32_bf16(al[rt], bh[ct], acc[rt][ct], 0, 0, 0);
        }
    }
    __syncthreads();
  }
#pragma unroll
  for (int rt = 0; rt < 2; ++rt)
#pragma unroll
    for (int r = 0; r < 4; ++r) {
      int row = wr * 32 + rt * 16 + kblk * 4 + r;
      int t_ = pair_token[row0 + row];
      if (t_ >= 0) {
        float g = pair_gate[row0 + row];
#pragma unroll
        for (int ct = 0; ct < 4; ++ct) {
          int n = n0 + wc * 64 + ct * 16 + lrow;
          atomicAdd(out + (size_t)t_ * D_MOD + n, g * acc[rt][ct][r]);
        }
      }
    }
}

// ---------------- launch ----------------

extern "C" void kernel_launch(void* const* d_in, const int* in_sizes, int n_in,
                              void* d_out, int out_size, void* d_ws, size_t ws_size,
                              hipStream_t stream) {
  const float* x  = (const float*)d_in[0];
  const float* Wg = (const float*)d_in[1];
  const float* bg = (const float*)d_in[2];
  const float* W1 = (const float*)d_in[3];
  const float* b1 = (const float*)d_in[4];
  const float* W2 = (const float*)d_in[5];
  const float* b2 = (const float*)d_in[6];
  float* out = (float*)d_out;

  char* ws = (char*)d_ws;
  size_t off = 0;
  auto take = [&](size_t bytes) -> char* {
    char* p = ws + off;
    off += (bytes + 255) & ~(size_t)255;
    return p;
  };
  const size_t WELEMS = (size_t)N_EXP * D_MOD * D_FF;   // 8,388,608
  unsigned short* W1h = (unsigned short*)take(WELEMS * 2);
  unsigned short* W1l = (unsigned short*)take(WELEMS * 2);
  unsigned short* W2h = (unsigned short*)take(WELEMS * 2);
  unsigned short* W2l = (unsigned short*)take(WELEMS * 2);
  int*   top_i      = (int*)take((size_t)T_TOKENS * 2 * 4);
  float* gates      = (float*)take((size_t)T_TOKENS * 2 * 4);
  int*   counts     = (int*)take(64);
  int*   offsets    = (int*)take(64);
  int*   cursor     = (int*)take(64);
  int*   pair_token = (int*)take((size_t)P_CAP * 4);
  float* pair_gate  = (float*)take((size_t)P_CAP * 4);
  size_t h_avail = (ws_size > off) ? ws_size - off : 0;
  int rows_cap = (int)(h_avail / ((size_t)D_FF * 4));   // hi+lo bf16 = 4B/elem
  rows_cap &= ~(TPAD - 1);
  if (rows_cap > P_CAP) rows_cap = P_CAP;
  if (rows_cap < TPAD) rows_cap = TPAD;
  unsigned short* h_hi = (unsigned short*)(ws + off);
  unsigned short* h_lo = h_hi + (size_t)rows_cap * D_FF;

  k_init<<<dim3((P_CAP + 255) / 256), dim3(256), 0, stream>>>(counts, pair_token, pair_gate);
  k_gate<<<dim3(T_TOKENS / 4), dim3(256), 0, stream>>>(x, Wg, bg, top_i, gates, counts);
  k_scan<<<dim3(1), dim3(64), 0, stream>>>(counts, offsets, cursor);
  k_scatter<<<dim3(T_TOKENS / 256), dim3(256), 0, stream>>>(top_i, gates, cursor, pair_token, pair_gate);
  k_outinit<<<dim3(T_TOKENS * D_MOD / 256), dim3(256), 0, stream>>>(top_i, gates, b2, out);
  // W1[e][512][2048] -> [e][2048][512] ; W2[e][2048][512] -> [e][512][2048]
  k_transpose<<<dim3(D_FF / 32, D_MOD / 32, N_EXP), dim3(256), 0, stream>>>(W1, W1h, W1l, D_MOD, D_FF);
  k_transpose<<<dim3(D_MOD / 32, D_FF / 32, N_EXP), dim3(256), 0, stream>>>(W2, W2h, W2l, D_FF, D_MOD);

  for (int rb = 0; rb < P_CAP; rb += rows_cap) {
    int left = P_CAP - rb;
    int rows = (rows_cap < left) ? rows_cap : left;
    k_ffn1<<<dim3(rows / TPAD, D_FF / 128), dim3(512), 0, stream>>>(
        x, W1h, W1l, b1, pair_token, offsets, h_hi, h_lo, rb);
    k_ffn2<<<dim3(rows / 64, D_MOD / 256, D_FF / 512), dim3(512), 0, stream>>>(
        h_hi, h_lo, W2h, W2l, pair_token, pair_gate, offsets, out, rb);
  }
}